// Round 14
// baseline (153.585 us; speedup 1.0000x reference)
//
#include <hip/hip_runtime.h>
#include <stdint.h>

#define NUM_LAYERS 24
#define LN_EPS 1e-5f
#define N_ROWS (256 * 8192)
#define ROWS_PER_ITER 128
#define NUM_ITERS (N_ROWS / ROWS_PER_ITER)   // 16384
#define NUM_BLOCKS 2048                       // 8192 waves -> 2 iters/wave

typedef __attribute__((ext_vector_type(4)))  uint32_t u32x4;   // packed frag bits
typedef __attribute__((ext_vector_type(8)))  __fp16   h16x8;   // MFMA A/B operand
typedef __attribute__((ext_vector_type(16))) float    f32x16;  // 32x32 MFMA acc
typedef __attribute__((ext_vector_type(2)))  float    f32x2;
typedef __attribute__((ext_vector_type(2)))  __fp16   h16x2;

// ---- f16 packing helpers ----
__device__ __forceinline__ uint32_t pk_f16_rtz(float lo, float hi) {
    h16x2 v = __builtin_amdgcn_cvt_pkrtz(lo, hi);   // v_cvt_pkrtz_f16_f32
    uint32_t u; __builtin_memcpy(&u, &v, 4);
    return u;
}
__device__ __forceinline__ uint32_t pk_f16_rne(float lo, float hi) {  // setup only
    __fp16 a = (__fp16)lo, b = (__fp16)hi;
    uint16_t ua, ub;
    __builtin_memcpy(&ua, &a, 2); __builtin_memcpy(&ub, &b, 2);
    return (uint32_t)ua | ((uint32_t)ub << 16);
}
__device__ __forceinline__ uint32_t pk_relu_f16(uint32_t d) {  // v_pk_max_f16
    h16x2 v; __builtin_memcpy(&v, &d, 4);
    h16x2 z = {(__fp16)0.0f, (__fp16)0.0f};
    v = __builtin_elementwise_max(v, z);
    uint32_t u; __builtin_memcpy(&u, &v, 4);
    return u;
}

union FragU { u32x4 u; h16x8 h; };

__device__ __forceinline__ h16x8 make_frag(uint32_t d0, uint32_t d1,
                                           uint32_t d2, uint32_t d3) {
    FragU f;
    f.u.x = d0; f.u.y = d1; f.u.z = d2; f.u.w = d3;
    return f.h;
}

#define MFMA(a, b, c) __builtin_amdgcn_mfma_f32_32x32x16_f16((a), (b), (c), 0, 0, 0)

// canonical hidden index k placed at layer1-output row-position p (sigma) —
// makes C1's C-layout register order equal the layer2 fragment K order.
__device__ __forceinline__ int sigma_k(int p) {
    int hh = (p >> 2) & 1;
    int base = (p & 31) - 4 * hh;            // {0-3,8-11,16-19,24-27}
    int r = (base & 3) + 4 * (base >> 3);    // [0,16)
    return 32 * (p >> 5) + 16 * (r >> 3) + 8 * hh + (r & 7);
}

__global__ __launch_bounds__(256, 3) void router_mfma(
    const float* __restrict__ x,
    const float* __restrict__ ln_w,
    const float* __restrict__ ln_b,
    const float* __restrict__ W1,
    const float* __restrict__ b1,
    const float* __restrict__ W2,
    const float* __restrict__ b2,
    const float* __restrict__ W3,
    const float* __restrict__ b3,
    float* __restrict__ out)
{
    // γ/β plane-major: s_ln[q*24 + lid] — conflict-free ds_read_b32 gather.
    __shared__ float s_ln[8 * NUM_LAYERS];

    const int t = threadIdx.x;
    if (t < 8 * NUM_LAYERS) {
        const int q = t & 7, lid = t >> 3;
        s_ln[q * NUM_LAYERS + lid] =
            (q < 4) ? ln_w[lid * 4 + q] : ln_b[lid * 4 + (q - 4)];
    }
    __syncthreads();

    const int lane = t & 63;
    const int wid  = t >> 6;
    const int n32  = lane & 31;
    const int h    = lane >> 5;

    // ---------- preload weight fragments ----------
    h16x8 a1f[2];
#pragma unroll
    for (int mt = 0; mt < 2; ++mt) {
        int p = mt * 32 + n32;
        int k = sigma_k(p);
        uint32_t d0 = pk_f16_rne(W1[k * 5 + 0], W1[k * 5 + 1]);
        uint32_t d1 = pk_f16_rne(W1[k * 5 + 2], W1[k * 5 + 3]);
        uint32_t d2 = pk_f16_rne(W1[k * 5 + 4], b1[k]);
        if (h) { d0 = 0; d1 = 0; d2 = 0; }   // A cols k>=8 are zero
        a1f[mt] = make_frag(d0, d1, d2, 0);
    }

    h16x8 w2f[4];
#pragma unroll
    for (int kt = 0; kt < 4; ++kt) {
        const float* wp = W2 + n32 * 64 + kt * 16 + h * 8;
        const float4 lo = *(const float4*)(wp);
        const float4 hi = *(const float4*)(wp + 4);
        w2f[kt] = make_frag(pk_f16_rne(lo.x, lo.y), pk_f16_rne(lo.z, lo.w),
                            pk_f16_rne(hi.x, hi.y), pk_f16_rne(hi.z, hi.w));
    }

    // C2^T C-layout: lane = data-row, reg r -> out-unit n = (r&3)+8*(r>>2)+4*h
    f32x16 c2init;
    f32x2 w3p[8];
#pragma unroll
    for (int r2 = 0; r2 < 8; ++r2) {
        const int n = ((2 * r2) & 3) + 8 * (r2 >> 1) + 4 * h;
        w3p[r2] = f32x2{W3[n], W3[n + 1]};
        c2init[2 * r2]     = b2[n];
        c2init[2 * r2 + 1] = b2[n + 1];
    }
    const float b3v = b3[0];
    const f32x2 z2 = {0.0f, 0.0f};

    f32x16 zf;
#pragma unroll
    for (int i = 0; i < 16; ++i) zf[i] = 0.0f;

    const int total_waves = NUM_BLOCKS * 4;   // 8192 -> 2 iters/wave
    const int w = blockIdx.x * 4 + wid;

    // ---- row loop: 128 rows/iter = two 64-row groups, ONE prefetch seam ----
    int it = w;
    {
        const float* p0 = x + (size_t)(it * ROWS_PER_ITER + lane) * 5;
        const float* p1 = x + (size_t)(it * ROWS_PER_ITER + 64 + lane) * 5;
        float4 c40 = *(const float4*)p0; float cl0 = p0[4];
        float4 c41 = *(const float4*)p1; float cl1 = p1[4];

        while (true) {
            const int nit = it + total_waves;
            const bool more = nit < NUM_ITERS;
            const size_t nb = (size_t)(more ? nit : it) * ROWS_PER_ITER;
            const float* n0 = x + (nb + lane) * 5;
            const float* n1 = x + (nb + 64 + lane) * 5;
            const float4 nv40 = *(const float4*)n0; const float nl0 = n0[4];
            const float4 nv41 = *(const float4*)n1; const float nl1 = n1[4];

            const int rowBase = it * ROWS_PER_ITER;

#pragma unroll
            for (int grp = 0; grp < 2; ++grp) {
                const float4 cv = grp ? c41 : c40;
                const float  cl = grp ? cl1 : cl0;
                const int gbase = rowBase + 64 * grp;

                // ---- LayerNorm of row (gbase + lane) ----
                int lid = (int)(cl * (float)NUM_LAYERS);
                lid = lid < 0 ? 0 : (lid > NUM_LAYERS - 1 ? NUM_LAYERS - 1 : lid);

                const float m  = (cv.x + cv.y + cv.z + cv.w) * 0.25f;
                const float d0 = cv.x - m, d1 = cv.y - m,
                            d2 = cv.z - m, d3 = cv.w - m;
                const float var = (d0 * d0 + d1 * d1 + d2 * d2 + d3 * d3) * 0.25f;
                const float r   = rsqrtf(var + LN_EPS);

                const float xn0 = fmaf(d0, r * s_ln[0 * 24 + lid], s_ln[4 * 24 + lid]);
                const float xn1 = fmaf(d1, r * s_ln[1 * 24 + lid], s_ln[5 * 24 + lid]);
                const float xn2 = fmaf(d2, r * s_ln[2 * 24 + lid], s_ln[6 * 24 + lid]);
                const float xn3 = fmaf(d3, r * s_ln[3 * 24 + lid], s_ln[7 * 24 + lid]);

                // packed normed features (+1.0 slot at q=5 for the b1 fold)
                const uint32_t e0 = pk_f16_rtz(xn0, xn1);
                const uint32_t e1 = pk_f16_rtz(xn2, xn3);
                const uint32_t e2 = pk_f16_rtz(cl, 1.0f);
                const uint32_t x0 = __shfl_xor((int)e0, 32, 64);
                const uint32_t x1 = __shfl_xor((int)e1, 32, 64);
                const uint32_t x2 = __shfl_xor((int)e2, 32, 64);

                const h16x8 bf_t0 = make_frag(e0, e1, e2, 0u);  // rows 0..31
                const h16x8 bf_t1 = make_frag(x0, x1, x2, 0u);  // rows 32..63

                // ---- layer 1: both tiles (4 independent MFMAs, intrinsics) --
                f32x16 c1a0 = MFMA(a1f[0], bf_t0, zf);
                f32x16 c1b0 = MFMA(a1f[1], bf_t0, zf);
                f32x16 c1a1 = MFMA(a1f[0], bf_t1, zf);
                f32x16 c1b1 = MFMA(a1f[1], bf_t1, zf);

                // ---- repack both tiles ----
                h16x8 h1f0[4], h1f1[4];
#pragma unroll
                for (int kt = 0; kt < 4; ++kt) {
                    const f32x16& c1 = (kt < 2) ? c1a0 : c1b0;
                    const int roff = 8 * (kt & 1);
                    uint32_t dw[4];
#pragma unroll
                    for (int d = 0; d < 4; ++d)
                        dw[d] = pk_relu_f16(
                            pk_f16_rtz(c1[roff + 2 * d], c1[roff + 2 * d + 1]));
                    h1f0[kt] = make_frag(dw[0], dw[1], dw[2], dw[3]);
                }
#pragma unroll
                for (int kt = 0; kt < 4; ++kt) {
                    const f32x16& c1 = (kt < 2) ? c1a1 : c1b1;
                    const int roff = 8 * (kt & 1);
                    uint32_t dw[4];
#pragma unroll
                    for (int d = 0; d < 4; ++d)
                        dw[d] = pk_relu_f16(
                            pk_f16_rtz(c1[roff + 2 * d], c1[roff + 2 * d + 1]));
                    h1f1[kt] = make_frag(dw[0], dw[1], dw[2], dw[3]);
                }

                // ---- layer 2: two 4-deep chains (intrinsics) ----
                f32x16 c2_0 = c2init, c2_1 = c2init;
#pragma unroll
                for (int kt = 0; kt < 4; ++kt) {
                    c2_0 = MFMA(w2f[kt], h1f0[kt], c2_0);
                    c2_1 = MFMA(w2f[kt], h1f1[kt], c2_1);
                }

                // ---- layer 3: relu -> dot W3 over 16 regs, both tiles ----
                f32x2 acc0 = z2, acc1 = z2;
#pragma unroll
                for (int r2 = 0; r2 < 8; ++r2) {
                    f32x2 v0 = {c2_0[2 * r2], c2_0[2 * r2 + 1]};
                    f32x2 v1 = {c2_1[2 * r2], c2_1[2 * r2 + 1]};
                    v0 = __builtin_elementwise_max(v0, z2);
                    v1 = __builtin_elementwise_max(v1, z2);
                    acc0 = v0 * w3p[r2] + acc0;
                    acc1 = v1 * w3p[r2] + acc1;
                }
                float q0 = acc0.x + acc0.y;
                float q1 = acc1.x + acc1.y;
                q0 += __shfl_xor(q0, 32, 64);
                q1 += __shfl_xor(q1, 32, 64);

                out[gbase + lane] = (h ? q1 : q0) + b3v;
            }

            if (!more) break;
            it = nit;
            c40 = nv40; cl0 = nl0; c41 = nv41; cl1 = nl1;
        }
    }
}

extern "C" void kernel_launch(void* const* d_in, const int* in_sizes, int n_in,
                              void* d_out, int out_size, void* d_ws, size_t ws_size,
                              hipStream_t stream) {
    const float* x    = (const float*)d_in[0];
    const float* ln_w = (const float*)d_in[1];
    const float* ln_b = (const float*)d_in[2];
    const float* W1   = (const float*)d_in[3];
    const float* b1   = (const float*)d_in[4];
    const float* W2   = (const float*)d_in[5];
    const float* b2   = (const float*)d_in[6];
    const float* W3   = (const float*)d_in[7];
    const float* b3   = (const float*)d_in[8];
    float* out = (float*)d_out;

    router_mfma<<<NUM_BLOCKS, 256, 0, stream>>>(x, ln_w, ln_b, W1, b1, W2, b2,
                                                W3, b3, out);
}

// Round 15
// 107.200 us; speedup vs baseline: 1.4327x; 1.4327x over previous
//
#include <hip/hip_runtime.h>
#include <stdint.h>

#define NUM_LAYERS 24
#define LN_EPS 1e-5f
#define N_ROWS (256 * 8192)
#define ROWS_PER_ITER 128
#define NUM_ITERS (N_ROWS / ROWS_PER_ITER)   // 16384
#define NUM_BLOCKS 2048                       // 8192 waves -> 2 iters/wave

typedef __attribute__((ext_vector_type(4)))  uint32_t u32x4;   // MFMA A/B operand
typedef __attribute__((ext_vector_type(16))) float    f32x16;  // 32x32 MFMA acc
typedef __attribute__((ext_vector_type(2)))  float    f32x2;
typedef __attribute__((ext_vector_type(2)))  __fp16   h16x2;

// ---- f16 packing helpers ----
__device__ __forceinline__ uint32_t pk_f16_rtz(float lo, float hi) {
    h16x2 v = __builtin_amdgcn_cvt_pkrtz(lo, hi);   // v_cvt_pkrtz_f16_f32
    uint32_t u; __builtin_memcpy(&u, &v, 4);
    return u;
}
__device__ __forceinline__ uint32_t pk_f16_rne(float lo, float hi) {  // setup only
    __fp16 a = (__fp16)lo, b = (__fp16)hi;
    uint16_t ua, ub;
    __builtin_memcpy(&ua, &a, 2); __builtin_memcpy(&ub, &b, 2);
    return (uint32_t)ua | ((uint32_t)ub << 16);
}
__device__ __forceinline__ uint32_t pk_relu_f16(uint32_t d) {  // v_pk_max_f16
    h16x2 v; __builtin_memcpy(&v, &d, 4);
    h16x2 z = {(__fp16)0.0f, (__fp16)0.0f};
    v = __builtin_elementwise_max(v, z);
    uint32_t u; __builtin_memcpy(&u, &v, 4);
    return u;
}

__device__ __forceinline__ u32x4 make_frag(uint32_t d0, uint32_t d1,
                                           uint32_t d2, uint32_t d3) {
    u32x4 f; f.x = d0; f.y = d1; f.z = d2; f.w = d3;
    return f;
}

// ---- phase-level inline-asm MFMA blocks (VGPR form, single s_nop guard) ----
__device__ __forceinline__ void mfma_l1(f32x16& d0, f32x16& d1,
                                        f32x16& d2, f32x16& d3,
                                        const u32x4& a0, const u32x4& a1,
                                        const u32x4& b0, const u32x4& b1) {
    asm("s_nop 2\n\t"
        "v_mfma_f32_32x32x16_f16 %0, %4, %6, 0\n\t"
        "v_mfma_f32_32x32x16_f16 %1, %5, %6, 0\n\t"
        "v_mfma_f32_32x32x16_f16 %2, %4, %7, 0\n\t"
        "v_mfma_f32_32x32x16_f16 %3, %5, %7, 0"
        : "=&v"(d0), "=&v"(d1), "=&v"(d2), "=&v"(d3)
        : "v"(a0), "v"(a1), "v"(b0), "v"(b1));
}
__device__ __forceinline__ void mfma_l2(f32x16& c0, f32x16& c1, const f32x16& cinit,
                                        const u32x4& w0, const u32x4& w1,
                                        const u32x4& w2, const u32x4& w3,
                                        const u32x4& h00, const u32x4& h01,
                                        const u32x4& h02, const u32x4& h03,
                                        const u32x4& h10, const u32x4& h11,
                                        const u32x4& h12, const u32x4& h13) {
    asm("s_nop 2\n\t"
        "v_mfma_f32_32x32x16_f16 %0, %3, %7, %2\n\t"
        "v_mfma_f32_32x32x16_f16 %1, %3, %11, %2\n\t"
        "v_mfma_f32_32x32x16_f16 %0, %4, %8, %0\n\t"
        "v_mfma_f32_32x32x16_f16 %1, %4, %12, %1\n\t"
        "v_mfma_f32_32x32x16_f16 %0, %5, %9, %0\n\t"
        "v_mfma_f32_32x32x16_f16 %1, %5, %13, %1\n\t"
        "v_mfma_f32_32x32x16_f16 %0, %6, %10, %0\n\t"
        "v_mfma_f32_32x32x16_f16 %1, %6, %14, %1"
        : "=&v"(c0), "=&v"(c1)
        : "v"(cinit), "v"(w0), "v"(w1), "v"(w2), "v"(w3),
          "v"(h00), "v"(h01), "v"(h02), "v"(h03),
          "v"(h10), "v"(h11), "v"(h12), "v"(h13));
}
__device__ __forceinline__ void mfma_fence2(f32x16& c0, f32x16& c1) {
    asm volatile("s_nop 7\n\ts_nop 7\n\ts_nop 7" : "+v"(c0), "+v"(c1));
}
__device__ __forceinline__ void mfma_fence4(f32x16& c0, f32x16& c1,
                                            f32x16& c2, f32x16& c3) {
    asm volatile("s_nop 7\n\ts_nop 7\n\ts_nop 7"
                 : "+v"(c0), "+v"(c1), "+v"(c2), "+v"(c3));
}

// canonical hidden index k placed at layer1-output row-position p (sigma) —
// makes C1's C-layout register order equal the layer2 fragment K order.
__device__ __forceinline__ int sigma_k(int p) {
    int hh = (p >> 2) & 1;
    int base = (p & 31) - 4 * hh;            // {0-3,8-11,16-19,24-27}
    int r = (base & 3) + 4 * (base >> 3);    // [0,16)
    return 32 * (p >> 5) + 16 * (r >> 3) + 8 * hh + (r & 7);
}

__global__ __launch_bounds__(256, 3) void router_mfma(
    const float* __restrict__ x,
    const float* __restrict__ ln_w,
    const float* __restrict__ ln_b,
    const float* __restrict__ W1,
    const float* __restrict__ b1,
    const float* __restrict__ W2,
    const float* __restrict__ b2,
    const float* __restrict__ W3,
    const float* __restrict__ b3,
    float* __restrict__ out)
{
    // ---- block-cooperative weight-fragment tables in LDS ----
    // (scattered weight gathers once per BLOCK, not once per WAVE)
    __shared__ uint32_t s_a1[2 * 64 * 4];   // a1f[mt][lane] as 4 dwords
    __shared__ uint32_t s_w2[4 * 64 * 4];   // w2f[kt][lane] as 4 dwords
    __shared__ float    s_w3[8 * 64 * 2];   // w3p[r2][lane] pair
    __shared__ float    s_b2[8 * 64 * 2];   // b2 pair for c2init
    __shared__ float    s_ln[8 * NUM_LAYERS];

    const int t = threadIdx.x;

    // γ/β plane-major (conflict-free gather later)
    if (t < 8 * NUM_LAYERS) {
        const int q = t & 7, lid = t >> 3;
        s_ln[q * NUM_LAYERS + lid] =
            (q < 4) ? ln_w[lid * 4 + q] : ln_b[lid * 4 + (q - 4)];
    }
    // a1f table: 128 entries (mt, lane)
    if (t < 128) {
        const int mt = t >> 6, ln = t & 63;
        const int n32l = ln & 31, hl = ln >> 5;
        uint32_t d0 = 0, d1 = 0, d2 = 0;
        if (!hl) {                       // A cols k>=8 are zero
            const int k = sigma_k(mt * 32 + n32l);
            d0 = pk_f16_rne(W1[k * 5 + 0], W1[k * 5 + 1]);
            d1 = pk_f16_rne(W1[k * 5 + 2], W1[k * 5 + 3]);
            d2 = pk_f16_rne(W1[k * 5 + 4], b1[k]);
        }
        uint32_t* p = &s_a1[(mt * 64 + ln) * 4];
        p[0] = d0; p[1] = d1; p[2] = d2; p[3] = 0;
    }
    // w2f table: 256 entries (kt, lane) — one per thread
    {
        const int kt = t >> 6, ln = t & 63;
        const int n32l = ln & 31, hl = ln >> 5;
        const float* wp = W2 + n32l * 64 + kt * 16 + hl * 8;
        const float4 lo = *(const float4*)(wp);
        const float4 hi = *(const float4*)(wp + 4);
        uint32_t* p = &s_w2[(kt * 64 + ln) * 4];
        p[0] = pk_f16_rne(lo.x, lo.y);
        p[1] = pk_f16_rne(lo.z, lo.w);
        p[2] = pk_f16_rne(hi.x, hi.y);
        p[3] = pk_f16_rne(hi.z, hi.w);
    }
    // w3/b2 pair tables: 512 entries (r2, lane) — two per thread
#pragma unroll
    for (int e = t; e < 512; e += 256) {
        const int r2 = e >> 6, ln = e & 63;
        const int hl = ln >> 5;
        const int n = ((2 * r2) & 3) + 8 * (r2 >> 1) + 4 * hl;
        s_w3[e * 2 + 0] = W3[n];
        s_w3[e * 2 + 1] = W3[n + 1];
        s_b2[e * 2 + 0] = b2[n];
        s_b2[e * 2 + 1] = b2[n + 1];
    }
    __syncthreads();

    const int lane = t & 63;
    const int wid  = t >> 6;
    const int h    = lane >> 5;

    // ---- per-wave fragment loads from LDS (wide, conflict-free) ----
    u32x4 a1f[2], w2f[4];
#pragma unroll
    for (int mt = 0; mt < 2; ++mt)
        a1f[mt] = *(const u32x4*)&s_a1[(mt * 64 + lane) * 4];
#pragma unroll
    for (int kt = 0; kt < 4; ++kt)
        w2f[kt] = *(const u32x4*)&s_w2[(kt * 64 + lane) * 4];

    f32x16 c2init;
    f32x2 w3p[8];
#pragma unroll
    for (int r2 = 0; r2 < 8; ++r2) {
        w3p[r2] = *(const f32x2*)&s_w3[(r2 * 64 + lane) * 2];
        const f32x2 bp = *(const f32x2*)&s_b2[(r2 * 64 + lane) * 2];
        c2init[2 * r2]     = bp.x;
        c2init[2 * r2 + 1] = bp.y;
    }
    const float b3v = b3[0];
    const f32x2 z2 = {0.0f, 0.0f};

    const int total_waves = NUM_BLOCKS * 4;   // 8192 -> 2 iters/wave
    const int w = blockIdx.x * 4 + wid;

    // ---- row loop: 128 rows/iter = two 64-row groups, one prefetch seam ----
    int it = w;
    {
        const float* p0 = x + (size_t)(it * ROWS_PER_ITER + lane) * 5;
        const float* p1 = x + (size_t)(it * ROWS_PER_ITER + 64 + lane) * 5;
        float4 c40 = *(const float4*)p0; float cl0 = p0[4];
        float4 c41 = *(const float4*)p1; float cl1 = p1[4];

        while (true) {
            const int nit = it + total_waves;
            const bool more = nit < NUM_ITERS;
            const size_t nb = (size_t)(more ? nit : it) * ROWS_PER_ITER;
            const float* n0 = x + (nb + lane) * 5;
            const float* n1 = x + (nb + 64 + lane) * 5;
            const float4 nv40 = *(const float4*)n0; const float nl0 = n0[4];
            const float4 nv41 = *(const float4*)n1; const float nl1 = n1[4];

            const int rowBase = it * ROWS_PER_ITER;

#pragma unroll
            for (int grp = 0; grp < 2; ++grp) {
                const float4 cv = grp ? c41 : c40;
                const float  cl = grp ? cl1 : cl0;
                const int gbase = rowBase + 64 * grp;

                // ---- LayerNorm of row (gbase + lane) ----
                int lid = (int)(cl * (float)NUM_LAYERS);
                lid = lid < 0 ? 0 : (lid > NUM_LAYERS - 1 ? NUM_LAYERS - 1 : lid);

                const float m  = (cv.x + cv.y + cv.z + cv.w) * 0.25f;
                const float d0 = cv.x - m, d1 = cv.y - m,
                            d2 = cv.z - m, d3 = cv.w - m;
                const float var = (d0 * d0 + d1 * d1 + d2 * d2 + d3 * d3) * 0.25f;
                const float r   = rsqrtf(var + LN_EPS);

                const float xn0 = fmaf(d0, r * s_ln[0 * 24 + lid], s_ln[4 * 24 + lid]);
                const float xn1 = fmaf(d1, r * s_ln[1 * 24 + lid], s_ln[5 * 24 + lid]);
                const float xn2 = fmaf(d2, r * s_ln[2 * 24 + lid], s_ln[6 * 24 + lid]);
                const float xn3 = fmaf(d3, r * s_ln[3 * 24 + lid], s_ln[7 * 24 + lid]);

                // packed normed features (+1.0 slot at q=5 for the b1 fold)
                const uint32_t e0 = pk_f16_rtz(xn0, xn1);
                const uint32_t e1 = pk_f16_rtz(xn2, xn3);
                const uint32_t e2 = pk_f16_rtz(cl, 1.0f);
                const uint32_t x0 = __shfl_xor((int)e0, 32, 64);
                const uint32_t x1 = __shfl_xor((int)e1, 32, 64);
                const uint32_t x2 = __shfl_xor((int)e2, 32, 64);

                const u32x4 bf_t0 = make_frag(e0, e1, e2, 0u);  // rows 0..31
                const u32x4 bf_t1 = make_frag(x0, x1, x2, 0u);  // rows 32..63

                // ---- layer 1: both tiles, one asm block ----
                f32x16 c1a0, c1b0, c1a1, c1b1;
                mfma_l1(c1a0, c1b0, c1a1, c1b1, a1f[0], a1f[1], bf_t0, bf_t1);
                mfma_fence4(c1a0, c1b0, c1a1, c1b1);

                // ---- repack both tiles ----
                u32x4 h1f0[4], h1f1[4];
#pragma unroll
                for (int kt = 0; kt < 4; ++kt) {
                    const f32x16& c1 = (kt < 2) ? c1a0 : c1b0;
                    const int roff = 8 * (kt & 1);
                    uint32_t dw[4];
#pragma unroll
                    for (int d = 0; d < 4; ++d)
                        dw[d] = pk_relu_f16(
                            pk_f16_rtz(c1[roff + 2 * d], c1[roff + 2 * d + 1]));
                    h1f0[kt] = make_frag(dw[0], dw[1], dw[2], dw[3]);
                }
#pragma unroll
                for (int kt = 0; kt < 4; ++kt) {
                    const f32x16& c1 = (kt < 2) ? c1a1 : c1b1;
                    const int roff = 8 * (kt & 1);
                    uint32_t dw[4];
#pragma unroll
                    for (int d = 0; d < 4; ++d)
                        dw[d] = pk_relu_f16(
                            pk_f16_rtz(c1[roff + 2 * d], c1[roff + 2 * d + 1]));
                    h1f1[kt] = make_frag(dw[0], dw[1], dw[2], dw[3]);
                }

                // ---- layer 2: two interleaved chains, one asm block ----
                f32x16 c2_0, c2_1;
                mfma_l2(c2_0, c2_1, c2init,
                        w2f[0], w2f[1], w2f[2], w2f[3],
                        h1f0[0], h1f0[1], h1f0[2], h1f0[3],
                        h1f1[0], h1f1[1], h1f1[2], h1f1[3]);
                mfma_fence2(c2_0, c2_1);

                // ---- layer 3: relu -> dot W3 over 16 regs, both tiles ----
                f32x2 acc0 = z2, acc1 = z2;
#pragma unroll
                for (int r2 = 0; r2 < 8; ++r2) {
                    f32x2 v0 = {c2_0[2 * r2], c2_0[2 * r2 + 1]};
                    f32x2 v1 = {c2_1[2 * r2], c2_1[2 * r2 + 1]};
                    v0 = __builtin_elementwise_max(v0, z2);
                    v1 = __builtin_elementwise_max(v1, z2);
                    acc0 = v0 * w3p[r2] + acc0;
                    acc1 = v1 * w3p[r2] + acc1;
                }
                float q0 = acc0.x + acc0.y;
                float q1 = acc1.x + acc1.y;
                q0 += __shfl_xor(q0, 32, 64);
                q1 += __shfl_xor(q1, 32, 64);

                out[gbase + lane] = (h ? q1 : q0) + b3v;
            }

            if (!more) break;
            it = nit;
            c40 = nv40; cl0 = nl0; c41 = nv41; cl1 = nl1;
        }
    }
}

extern "C" void kernel_launch(void* const* d_in, const int* in_sizes, int n_in,
                              void* d_out, int out_size, void* d_ws, size_t ws_size,
                              hipStream_t stream) {
    const float* x    = (const float*)d_in[0];
    const float* ln_w = (const float*)d_in[1];
    const float* ln_b = (const float*)d_in[2];
    const float* W1   = (const float*)d_in[3];
    const float* b1   = (const float*)d_in[4];
    const float* W2   = (const float*)d_in[5];
    const float* b2   = (const float*)d_in[6];
    const float* W3   = (const float*)d_in[7];
    const float* b3   = (const float*)d_in[8];
    float* out = (float*)d_out;

    router_mfma<<<NUM_BLOCKS, 256, 0, stream>>>(x, ln_w, ln_b, W1, b1, W2, b2,
                                                W3, b3, out);
}

// Round 16
// 106.626 us; speedup vs baseline: 1.4404x; 1.0054x over previous
//
#include <hip/hip_runtime.h>
#include <stdint.h>

#define NUM_LAYERS 24
#define LN_EPS 1e-5f
#define N_ROWS (256 * 8192)
#define NUM_BLOCKS 2048   // 8192 waves x 256 rows/wave = N_ROWS, straight-line

typedef __attribute__((ext_vector_type(4)))  uint32_t u32x4;   // MFMA A/B operand
typedef __attribute__((ext_vector_type(16))) float    f32x16;  // 32x32 MFMA acc
typedef __attribute__((ext_vector_type(2)))  float    f32x2;
typedef __attribute__((ext_vector_type(2)))  __fp16   h16x2;

// ---- f16 packing helpers ----
__device__ __forceinline__ uint32_t pk_f16_rtz(float lo, float hi) {
    h16x2 v = __builtin_amdgcn_cvt_pkrtz(lo, hi);   // v_cvt_pkrtz_f16_f32
    uint32_t u; __builtin_memcpy(&u, &v, 4);
    return u;
}
__device__ __forceinline__ uint32_t pk_f16_rne(float lo, float hi) {  // setup only
    __fp16 a = (__fp16)lo, b = (__fp16)hi;
    uint16_t ua, ub;
    __builtin_memcpy(&ua, &a, 2); __builtin_memcpy(&ub, &b, 2);
    return (uint32_t)ua | ((uint32_t)ub << 16);
}
__device__ __forceinline__ uint32_t pk_relu_f16(uint32_t d) {  // v_pk_max_f16
    h16x2 v; __builtin_memcpy(&v, &d, 4);
    h16x2 z = {(__fp16)0.0f, (__fp16)0.0f};
    v = __builtin_elementwise_max(v, z);
    uint32_t u; __builtin_memcpy(&u, &v, 4);
    return u;
}

__device__ __forceinline__ u32x4 make_frag(uint32_t d0, uint32_t d1,
                                           uint32_t d2, uint32_t d3) {
    u32x4 f; f.x = d0; f.y = d1; f.z = d2; f.w = d3;
    return f;
}

// ---- phase-level inline-asm MFMA blocks (VGPR form, single s_nop guard) ----
__device__ __forceinline__ void mfma_l1(f32x16& d0, f32x16& d1,
                                        f32x16& d2, f32x16& d3,
                                        const u32x4& a0, const u32x4& a1,
                                        const u32x4& b0, const u32x4& b1) {
    asm("s_nop 2\n\t"
        "v_mfma_f32_32x32x16_f16 %0, %4, %6, 0\n\t"
        "v_mfma_f32_32x32x16_f16 %1, %5, %6, 0\n\t"
        "v_mfma_f32_32x32x16_f16 %2, %4, %7, 0\n\t"
        "v_mfma_f32_32x32x16_f16 %3, %5, %7, 0"
        : "=&v"(d0), "=&v"(d1), "=&v"(d2), "=&v"(d3)
        : "v"(a0), "v"(a1), "v"(b0), "v"(b1));
}
__device__ __forceinline__ void mfma_l2(f32x16& c0, f32x16& c1, const f32x16& cinit,
                                        const u32x4& w0, const u32x4& w1,
                                        const u32x4& w2, const u32x4& w3,
                                        const u32x4& h00, const u32x4& h01,
                                        const u32x4& h02, const u32x4& h03,
                                        const u32x4& h10, const u32x4& h11,
                                        const u32x4& h12, const u32x4& h13) {
    asm("s_nop 2\n\t"
        "v_mfma_f32_32x32x16_f16 %0, %3, %7, %2\n\t"
        "v_mfma_f32_32x32x16_f16 %1, %3, %11, %2\n\t"
        "v_mfma_f32_32x32x16_f16 %0, %4, %8, %0\n\t"
        "v_mfma_f32_32x32x16_f16 %1, %4, %12, %1\n\t"
        "v_mfma_f32_32x32x16_f16 %0, %5, %9, %0\n\t"
        "v_mfma_f32_32x32x16_f16 %1, %5, %13, %1\n\t"
        "v_mfma_f32_32x32x16_f16 %0, %6, %10, %0\n\t"
        "v_mfma_f32_32x32x16_f16 %1, %6, %14, %1"
        : "=&v"(c0), "=&v"(c1)
        : "v"(cinit), "v"(w0), "v"(w1), "v"(w2), "v"(w3),
          "v"(h00), "v"(h01), "v"(h02), "v"(h03),
          "v"(h10), "v"(h11), "v"(h12), "v"(h13));
}
__device__ __forceinline__ void mfma_fence2(f32x16& c0, f32x16& c1) {
    asm volatile("s_nop 7\n\ts_nop 7\n\ts_nop 7" : "+v"(c0), "+v"(c1));
}
__device__ __forceinline__ void mfma_fence4(f32x16& c0, f32x16& c1,
                                            f32x16& c2, f32x16& c3) {
    asm volatile("s_nop 7\n\ts_nop 7\n\ts_nop 7"
                 : "+v"(c0), "+v"(c1), "+v"(c2), "+v"(c3));
}

// canonical hidden index k placed at layer1-output row-position p (sigma) —
// makes C1's C-layout register order equal the layer2 fragment K order.
__device__ __forceinline__ int sigma_k(int p) {
    int hh = (p >> 2) & 1;
    int base = (p & 31) - 4 * hh;            // {0-3,8-11,16-19,24-27}
    int r = (base & 3) + 4 * (base >> 3);    // [0,16)
    return 32 * (p >> 5) + 16 * (r >> 3) + 8 * hh + (r & 7);
}

__global__ __launch_bounds__(256, 2) void router_mfma(
    const float* __restrict__ x,
    const float* __restrict__ ln_w,
    const float* __restrict__ ln_b,
    const float* __restrict__ W1,
    const float* __restrict__ b1,
    const float* __restrict__ W2,
    const float* __restrict__ b2,
    const float* __restrict__ W3,
    const float* __restrict__ b3,
    float* __restrict__ out)
{
    // ---- block-cooperative weight-fragment tables in LDS (R15) ----
    __shared__ uint32_t s_a1[2 * 64 * 4];
    __shared__ uint32_t s_w2[4 * 64 * 4];
    __shared__ float    s_w3[8 * 64 * 2];
    __shared__ float    s_b2[8 * 64 * 2];
    __shared__ float    s_ln[8 * NUM_LAYERS];

    const int t = threadIdx.x;

    if (t < 8 * NUM_LAYERS) {
        const int q = t & 7, lid = t >> 3;
        s_ln[q * NUM_LAYERS + lid] =
            (q < 4) ? ln_w[lid * 4 + q] : ln_b[lid * 4 + (q - 4)];
    }
    if (t < 128) {
        const int mt = t >> 6, ln = t & 63;
        const int n32l = ln & 31, hl = ln >> 5;
        uint32_t d0 = 0, d1 = 0, d2 = 0;
        if (!hl) {
            const int k = sigma_k(mt * 32 + n32l);
            d0 = pk_f16_rne(W1[k * 5 + 0], W1[k * 5 + 1]);
            d1 = pk_f16_rne(W1[k * 5 + 2], W1[k * 5 + 3]);
            d2 = pk_f16_rne(W1[k * 5 + 4], b1[k]);
        }
        uint32_t* p = &s_a1[(mt * 64 + ln) * 4];
        p[0] = d0; p[1] = d1; p[2] = d2; p[3] = 0;
    }
    {
        const int kt = t >> 6, ln = t & 63;
        const int n32l = ln & 31, hl = ln >> 5;
        const float* wp = W2 + n32l * 64 + kt * 16 + hl * 8;
        const float4 lo = *(const float4*)(wp);
        const float4 hi = *(const float4*)(wp + 4);
        uint32_t* p = &s_w2[(kt * 64 + ln) * 4];
        p[0] = pk_f16_rne(lo.x, lo.y);
        p[1] = pk_f16_rne(lo.z, lo.w);
        p[2] = pk_f16_rne(hi.x, hi.y);
        p[3] = pk_f16_rne(hi.z, hi.w);
    }
#pragma unroll
    for (int e = t; e < 512; e += 256) {
        const int r2 = e >> 6, ln = e & 63;
        const int hl = ln >> 5;
        const int n = ((2 * r2) & 3) + 8 * (r2 >> 1) + 4 * hl;
        s_w3[e * 2 + 0] = W3[n];
        s_w3[e * 2 + 1] = W3[n + 1];
        s_b2[e * 2 + 0] = b2[n];
        s_b2[e * 2 + 1] = b2[n + 1];
    }
    __syncthreads();

    const int lane = t & 63;
    const int wid  = t >> 6;
    const int h    = lane >> 5;

    // ---- per-wave fragment loads from LDS (wide, conflict-free) ----
    u32x4 a1f[2], w2f[4];
#pragma unroll
    for (int mt = 0; mt < 2; ++mt)
        a1f[mt] = *(const u32x4*)&s_a1[(mt * 64 + lane) * 4];
#pragma unroll
    for (int kt = 0; kt < 4; ++kt)
        w2f[kt] = *(const u32x4*)&s_w2[(kt * 64 + lane) * 4];

    f32x16 c2init;
    f32x2 w3p[8];
#pragma unroll
    for (int r2 = 0; r2 < 8; ++r2) {
        w3p[r2] = *(const f32x2*)&s_w3[(r2 * 64 + lane) * 2];
        const f32x2 bp = *(const f32x2*)&s_b2[(r2 * 64 + lane) * 2];
        c2init[2 * r2]     = bp.x;
        c2init[2 * r2 + 1] = bp.y;
    }
    const float b3v = b3[0];
    const f32x2 z2 = {0.0f, 0.0f};

    // ---- straight line: this wave owns 256 consecutive rows (4 groups) ----
    const int w = blockIdx.x * 4 + wid;            // 0..8191
    const size_t rowBase = (size_t)w * 256;

    // load all 4 groups' x up front (8 independent VMEM ops)
    float4 cv[4];
    float  cl[4];
#pragma unroll
    for (int g = 0; g < 4; ++g) {
        const float* p = x + (rowBase + 64 * g + lane) * 5;
        cv[g] = *(const float4*)p;
        cl[g] = p[4];
    }

    // ---- batched LN + feature exchange for all 4 groups ----
    u32x4 bft[4][2];
#pragma unroll
    for (int g = 0; g < 4; ++g) {
        int lid = (int)(cl[g] * (float)NUM_LAYERS);
        lid = lid < 0 ? 0 : (lid > NUM_LAYERS - 1 ? NUM_LAYERS - 1 : lid);

        const float m  = (cv[g].x + cv[g].y + cv[g].z + cv[g].w) * 0.25f;
        const float d0 = cv[g].x - m, d1 = cv[g].y - m,
                    d2 = cv[g].z - m, d3 = cv[g].w - m;
        const float var = (d0 * d0 + d1 * d1 + d2 * d2 + d3 * d3) * 0.25f;
        const float r   = rsqrtf(var + LN_EPS);

        const float xn0 = fmaf(d0, r * s_ln[0 * 24 + lid], s_ln[4 * 24 + lid]);
        const float xn1 = fmaf(d1, r * s_ln[1 * 24 + lid], s_ln[5 * 24 + lid]);
        const float xn2 = fmaf(d2, r * s_ln[2 * 24 + lid], s_ln[6 * 24 + lid]);
        const float xn3 = fmaf(d3, r * s_ln[3 * 24 + lid], s_ln[7 * 24 + lid]);

        const uint32_t e0 = pk_f16_rtz(xn0, xn1);
        const uint32_t e1 = pk_f16_rtz(xn2, xn3);
        const uint32_t e2 = pk_f16_rtz(cl[g], 1.0f);
        const uint32_t x0 = __shfl_xor((int)e0, 32, 64);
        const uint32_t x1 = __shfl_xor((int)e1, 32, 64);
        const uint32_t x2 = __shfl_xor((int)e2, 32, 64);

        bft[g][0] = make_frag(e0, e1, e2, 0u);   // rows +0..31
        bft[g][1] = make_frag(x0, x1, x2, 0u);   // rows +32..63
    }

    // ---- per group: MFMA pipeline (R13 body, loop-free context) ----
#pragma unroll
    for (int g = 0; g < 4; ++g) {
        const size_t gbase = rowBase + 64 * g;

        f32x16 c1a0, c1b0, c1a1, c1b1;
        mfma_l1(c1a0, c1b0, c1a1, c1b1, a1f[0], a1f[1], bft[g][0], bft[g][1]);
        mfma_fence4(c1a0, c1b0, c1a1, c1b1);

        u32x4 h1f0[4], h1f1[4];
#pragma unroll
        for (int kt = 0; kt < 4; ++kt) {
            const f32x16& c1 = (kt < 2) ? c1a0 : c1b0;
            const int roff = 8 * (kt & 1);
            uint32_t dw[4];
#pragma unroll
            for (int d = 0; d < 4; ++d)
                dw[d] = pk_relu_f16(
                    pk_f16_rtz(c1[roff + 2 * d], c1[roff + 2 * d + 1]));
            h1f0[kt] = make_frag(dw[0], dw[1], dw[2], dw[3]);
        }
#pragma unroll
        for (int kt = 0; kt < 4; ++kt) {
            const f32x16& c1 = (kt < 2) ? c1a1 : c1b1;
            const int roff = 8 * (kt & 1);
            uint32_t dw[4];
#pragma unroll
            for (int d = 0; d < 4; ++d)
                dw[d] = pk_relu_f16(
                    pk_f16_rtz(c1[roff + 2 * d], c1[roff + 2 * d + 1]));
            h1f1[kt] = make_frag(dw[0], dw[1], dw[2], dw[3]);
        }

        f32x16 c2_0, c2_1;
        mfma_l2(c2_0, c2_1, c2init,
                w2f[0], w2f[1], w2f[2], w2f[3],
                h1f0[0], h1f0[1], h1f0[2], h1f0[3],
                h1f1[0], h1f1[1], h1f1[2], h1f1[3]);
        mfma_fence2(c2_0, c2_1);

        f32x2 acc0 = z2, acc1 = z2;
#pragma unroll
        for (int r2 = 0; r2 < 8; ++r2) {
            f32x2 v0 = {c2_0[2 * r2], c2_0[2 * r2 + 1]};
            f32x2 v1 = {c2_1[2 * r2], c2_1[2 * r2 + 1]};
            v0 = __builtin_elementwise_max(v0, z2);
            v1 = __builtin_elementwise_max(v1, z2);
            acc0 = v0 * w3p[r2] + acc0;
            acc1 = v1 * w3p[r2] + acc1;
        }
        float q0 = acc0.x + acc0.y;
        float q1 = acc1.x + acc1.y;
        q0 += __shfl_xor(q0, 32, 64);
        q1 += __shfl_xor(q1, 32, 64);

        out[gbase + lane] = (h ? q1 : q0) + b3v;
    }
}

extern "C" void kernel_launch(void* const* d_in, const int* in_sizes, int n_in,
                              void* d_out, int out_size, void* d_ws, size_t ws_size,
                              hipStream_t stream) {
    const float* x    = (const float*)d_in[0];
    const float* ln_w = (const float*)d_in[1];
    const float* ln_b = (const float*)d_in[2];
    const float* W1   = (const float*)d_in[3];
    const float* b1   = (const float*)d_in[4];
    const float* W2   = (const float*)d_in[5];
    const float* b2   = (const float*)d_in[6];
    const float* W3   = (const float*)d_in[7];
    const float* b3   = (const float*)d_in[8];
    float* out = (float*)d_out;

    router_mfma<<<NUM_BLOCKS, 256, 0, stream>>>(x, ln_w, ln_b, W1, b1, W2, b2,
                                                W3, b3, out);
}

// Round 17
// 104.633 us; speedup vs baseline: 1.4678x; 1.0190x over previous
//
#include <hip/hip_runtime.h>
#include <stdint.h>

#define NUM_LAYERS 24
#define LN_EPS 1e-5f
#define N_ROWS (256 * 8192)
#define NUM_BLOCKS 2048   // 8192 waves x 256 rows/wave, straight-line

typedef __attribute__((ext_vector_type(4)))  uint32_t u32x4;   // MFMA A/B operand
typedef __attribute__((ext_vector_type(16))) float    f32x16;  // 32x32 MFMA acc
typedef __attribute__((ext_vector_type(2)))  float    f32x2;
typedef __attribute__((ext_vector_type(2)))  __fp16   h16x2;

// ---- f16 packing helpers ----
__device__ __forceinline__ uint32_t pk_f16_rtz(float lo, float hi) {
    h16x2 v = __builtin_amdgcn_cvt_pkrtz(lo, hi);   // v_cvt_pkrtz_f16_f32
    uint32_t u; __builtin_memcpy(&u, &v, 4);
    return u;
}
__device__ __forceinline__ uint32_t pk_f16_rne(float lo, float hi) {  // setup only
    __fp16 a = (__fp16)lo, b = (__fp16)hi;
    uint16_t ua, ub;
    __builtin_memcpy(&ua, &a, 2); __builtin_memcpy(&ub, &b, 2);
    return (uint32_t)ua | ((uint32_t)ub << 16);
}
__device__ __forceinline__ uint32_t pk_relu_f16(uint32_t d) {  // v_pk_max_f16
    h16x2 v; __builtin_memcpy(&v, &d, 4);
    h16x2 z = {(__fp16)0.0f, (__fp16)0.0f};
    v = __builtin_elementwise_max(v, z);
    uint32_t u; __builtin_memcpy(&u, &v, 4);
    return u;
}

__device__ __forceinline__ u32x4 make_frag(uint32_t d0, uint32_t d1,
                                           uint32_t d2, uint32_t d3) {
    u32x4 f; f.x = d0; f.y = d1; f.z = d2; f.w = d3;
    return f;
}

// ---- inline-asm MFMA blocks (VGPR form, single s_nop guard) ----
// Layer 1, ONE tile: 2 independent MFMAs, C = inline 0 (32 transient acc regs).
__device__ __forceinline__ void mfma_l1(f32x16& d0, f32x16& d1,
                                        const u32x4& a0, const u32x4& a1,
                                        const u32x4& b) {
    asm("s_nop 2\n\t"
        "v_mfma_f32_32x32x16_f16 %0, %2, %4, 0\n\t"
        "v_mfma_f32_32x32x16_f16 %1, %3, %4, 0"
        : "=&v"(d0), "=&v"(d1)
        : "v"(a0), "v"(a1), "v"(b));
}
// Layer 2: two interleaved 4-deep chains, C = inline 0 (b2 added in epilogue).
__device__ __forceinline__ void mfma_l2z(f32x16& c0, f32x16& c1,
                                         const u32x4& w0, const u32x4& w1,
                                         const u32x4& w2, const u32x4& w3,
                                         const u32x4& h00, const u32x4& h01,
                                         const u32x4& h02, const u32x4& h03,
                                         const u32x4& h10, const u32x4& h11,
                                         const u32x4& h12, const u32x4& h13) {
    asm("s_nop 2\n\t"
        "v_mfma_f32_32x32x16_f16 %0, %2, %6, 0\n\t"
        "v_mfma_f32_32x32x16_f16 %1, %2, %10, 0\n\t"
        "v_mfma_f32_32x32x16_f16 %0, %3, %7, %0\n\t"
        "v_mfma_f32_32x32x16_f16 %1, %3, %11, %1\n\t"
        "v_mfma_f32_32x32x16_f16 %0, %4, %8, %0\n\t"
        "v_mfma_f32_32x32x16_f16 %1, %4, %12, %1\n\t"
        "v_mfma_f32_32x32x16_f16 %0, %5, %9, %0\n\t"
        "v_mfma_f32_32x32x16_f16 %1, %5, %13, %1"
        : "=&v"(c0), "=&v"(c1)
        : "v"(w0), "v"(w1), "v"(w2), "v"(w3),
          "v"(h00), "v"(h01), "v"(h02), "v"(h03),
          "v"(h10), "v"(h11), "v"(h12), "v"(h13));
}
__device__ __forceinline__ void mfma_fence2(f32x16& c0, f32x16& c1) {
    asm volatile("s_nop 7\n\ts_nop 7\n\ts_nop 7" : "+v"(c0), "+v"(c1));
}

// canonical hidden index k placed at layer1-output row-position p (sigma) —
// makes C1's C-layout register order equal the layer2 fragment K order.
__device__ __forceinline__ int sigma_k(int p) {
    int hh = (p >> 2) & 1;
    int base = (p & 31) - 4 * hh;            // {0-3,8-11,16-19,24-27}
    int r = (base & 3) + 4 * (base >> 3);    // [0,16)
    return 32 * (p >> 5) + 16 * (r >> 3) + 8 * hh + (r & 7);
}

__global__ __launch_bounds__(256, 4) void router_mfma(
    const float* __restrict__ x,
    const float* __restrict__ ln_w,
    const float* __restrict__ ln_b,
    const float* __restrict__ W1,
    const float* __restrict__ b1,
    const float* __restrict__ W2,
    const float* __restrict__ b2,
    const float* __restrict__ W3,
    const float* __restrict__ b3,
    float* __restrict__ out)
{
    // ---- block-cooperative weight tables in LDS ----
    __shared__ uint32_t s_a1[2 * 64 * 4];   // a1f[mt][lane] 4 dwords
    __shared__ uint32_t s_w2[4 * 64 * 4];   // w2f[kt][lane] 4 dwords
    __shared__ float    s_wb[8 * 64 * 4];   // {w3x,w3y,b2x,b2y} per (r2,lane)
    __shared__ float    s_ln[8 * NUM_LAYERS];

    const int t = threadIdx.x;

    if (t < 8 * NUM_LAYERS) {
        const int q = t & 7, lid = t >> 3;
        s_ln[q * NUM_LAYERS + lid] =
            (q < 4) ? ln_w[lid * 4 + q] : ln_b[lid * 4 + (q - 4)];
    }
    if (t < 128) {
        const int mt = t >> 6, ln = t & 63;
        const int n32l = ln & 31, hl = ln >> 5;
        uint32_t d0 = 0, d1 = 0, d2 = 0;
        if (!hl) {                       // A cols k>=8 are zero
            const int k = sigma_k(mt * 32 + n32l);
            d0 = pk_f16_rne(W1[k * 5 + 0], W1[k * 5 + 1]);
            d1 = pk_f16_rne(W1[k * 5 + 2], W1[k * 5 + 3]);
            d2 = pk_f16_rne(W1[k * 5 + 4], b1[k]);
        }
        uint32_t* p = &s_a1[(mt * 64 + ln) * 4];
        p[0] = d0; p[1] = d1; p[2] = d2; p[3] = 0;
    }
    {
        const int kt = t >> 6, ln = t & 63;
        const int n32l = ln & 31, hl = ln >> 5;
        const float* wp = W2 + n32l * 64 + kt * 16 + hl * 8;
        const float4 lo = *(const float4*)(wp);
        const float4 hi = *(const float4*)(wp + 4);
        uint32_t* p = &s_w2[(kt * 64 + ln) * 4];
        p[0] = pk_f16_rne(lo.x, lo.y);
        p[1] = pk_f16_rne(lo.z, lo.w);
        p[2] = pk_f16_rne(hi.x, hi.y);
        p[3] = pk_f16_rne(hi.z, hi.w);
    }
#pragma unroll
    for (int e = t; e < 512; e += 256) {
        const int r2 = e >> 6, ln = e & 63;
        const int hl = ln >> 5;
        const int n = ((2 * r2) & 3) + 8 * (r2 >> 1) + 4 * hl;
        float* p = &s_wb[e * 4];
        p[0] = W3[n]; p[1] = W3[n + 1];
        p[2] = b2[n]; p[3] = b2[n + 1];
    }
    __syncthreads();

    const int lane = t & 63;
    const int wid  = t >> 6;
    const int h    = lane >> 5;

    // ---- per-wave persistent fragments (24 regs) ----
    u32x4 a1f[2], w2f[4];
#pragma unroll
    for (int mt = 0; mt < 2; ++mt)
        a1f[mt] = *(const u32x4*)&s_a1[(mt * 64 + lane) * 4];
#pragma unroll
    for (int kt = 0; kt < 4; ++kt)
        w2f[kt] = *(const u32x4*)&s_w2[(kt * 64 + lane) * 4];

    const float b3v = b3[0];
    const f32x2 z2 = {0.0f, 0.0f};

    // ---- straight line: this wave owns 256 consecutive rows (4 groups) ----
    const int w = blockIdx.x * 4 + wid;            // 0..8191
    const size_t rowBase = (size_t)w * 256;

    // issue ALL x loads up front (8 independent VMEM ops, latency overlapped)
    float4 cv[4];
    float  cl[4];
#pragma unroll
    for (int g = 0; g < 4; ++g) {
        const float* p = x + (rowBase + 64 * g + lane) * 5;
        cv[g] = *(const float4*)p;
        cl[g] = p[4];
    }

#pragma unroll
    for (int g = 0; g < 4; ++g) {
        const size_t gbase = rowBase + 64 * g;

        // ---- LayerNorm of row (gbase + lane) ----
        int lid = (int)(cl[g] * (float)NUM_LAYERS);
        lid = lid < 0 ? 0 : (lid > NUM_LAYERS - 1 ? NUM_LAYERS - 1 : lid);

        const float m  = (cv[g].x + cv[g].y + cv[g].z + cv[g].w) * 0.25f;
        const float d0 = cv[g].x - m, d1 = cv[g].y - m,
                    d2 = cv[g].z - m, d3 = cv[g].w - m;
        const float var = (d0 * d0 + d1 * d1 + d2 * d2 + d3 * d3) * 0.25f;
        const float r   = rsqrtf(var + LN_EPS);

        const float xn0 = fmaf(d0, r * s_ln[0 * 24 + lid], s_ln[4 * 24 + lid]);
        const float xn1 = fmaf(d1, r * s_ln[1 * 24 + lid], s_ln[5 * 24 + lid]);
        const float xn2 = fmaf(d2, r * s_ln[2 * 24 + lid], s_ln[6 * 24 + lid]);
        const float xn3 = fmaf(d3, r * s_ln[3 * 24 + lid], s_ln[7 * 24 + lid]);

        // packed normed features (+1.0 slot at q=5 for the b1 fold)
        const uint32_t e0 = pk_f16_rtz(xn0, xn1);
        const uint32_t e1 = pk_f16_rtz(xn2, xn3);
        const uint32_t e2 = pk_f16_rtz(cl[g], 1.0f);
        const uint32_t x0 = __shfl_xor((int)e0, 32, 64);
        const uint32_t x1 = __shfl_xor((int)e1, 32, 64);
        const uint32_t x2 = __shfl_xor((int)e2, 32, 64);

        const u32x4 bf_t0 = make_frag(e0, e1, e2, 0u);   // rows +0..31
        const u32x4 bf_t1 = make_frag(x0, x1, x2, 0u);   // rows +32..63

        // ---- layer 1, tile 0 (32 transient acc regs, repacked immediately) --
        u32x4 h1f0[4], h1f1[4];
        {
            f32x16 c1a, c1b;
            mfma_l1(c1a, c1b, a1f[0], a1f[1], bf_t0);
            mfma_fence2(c1a, c1b);
#pragma unroll
            for (int kt = 0; kt < 4; ++kt) {
                const f32x16& c1 = (kt < 2) ? c1a : c1b;
                const int roff = 8 * (kt & 1);
                uint32_t dw[4];
#pragma unroll
                for (int d = 0; d < 4; ++d)
                    dw[d] = pk_relu_f16(
                        pk_f16_rtz(c1[roff + 2 * d], c1[roff + 2 * d + 1]));
                h1f0[kt] = make_frag(dw[0], dw[1], dw[2], dw[3]);
            }
        }
        // ---- layer 1, tile 1 ----
        {
            f32x16 c1a, c1b;
            mfma_l1(c1a, c1b, a1f[0], a1f[1], bf_t1);
            mfma_fence2(c1a, c1b);
#pragma unroll
            for (int kt = 0; kt < 4; ++kt) {
                const f32x16& c1 = (kt < 2) ? c1a : c1b;
                const int roff = 8 * (kt & 1);
                uint32_t dw[4];
#pragma unroll
                for (int d = 0; d < 4; ++d)
                    dw[d] = pk_relu_f16(
                        pk_f16_rtz(c1[roff + 2 * d], c1[roff + 2 * d + 1]));
                h1f1[kt] = make_frag(dw[0], dw[1], dw[2], dw[3]);
            }
        }

        // ---- layer 2: two interleaved chains, C = inline 0 ----
        f32x16 c2_0, c2_1;
        mfma_l2z(c2_0, c2_1,
                 w2f[0], w2f[1], w2f[2], w2f[3],
                 h1f0[0], h1f0[1], h1f0[2], h1f0[3],
                 h1f1[0], h1f1[1], h1f1[2], h1f1[3]);
        mfma_fence2(c2_0, c2_1);

        // ---- layer 3: +b2, relu, dot W3 (weights streamed from LDS) ----
        f32x2 acc0 = z2, acc1 = z2;
#pragma unroll
        for (int r2 = 0; r2 < 8; ++r2) {
            const float4 wb = *(const float4*)&s_wb[(r2 * 64 + lane) * 4];
            f32x2 v0 = {c2_0[2 * r2] + wb.z, c2_0[2 * r2 + 1] + wb.w};
            f32x2 v1 = {c2_1[2 * r2] + wb.z, c2_1[2 * r2 + 1] + wb.w};
            v0 = __builtin_elementwise_max(v0, z2);
            v1 = __builtin_elementwise_max(v1, z2);
            const f32x2 w3v = {wb.x, wb.y};
            acc0 = v0 * w3v + acc0;
            acc1 = v1 * w3v + acc1;
        }
        float q0 = acc0.x + acc0.y;
        float q1 = acc1.x + acc1.y;
        q0 += __shfl_xor(q0, 32, 64);
        q1 += __shfl_xor(q1, 32, 64);

        out[gbase + lane] = (h ? q1 : q0) + b3v;
    }
}

extern "C" void kernel_launch(void* const* d_in, const int* in_sizes, int n_in,
                              void* d_out, int out_size, void* d_ws, size_t ws_size,
                              hipStream_t stream) {
    const float* x    = (const float*)d_in[0];
    const float* ln_w = (const float*)d_in[1];
    const float* ln_b = (const float*)d_in[2];
    const float* W1   = (const float*)d_in[3];
    const float* b1   = (const float*)d_in[4];
    const float* W2   = (const float*)d_in[5];
    const float* b2   = (const float*)d_in[6];
    const float* W3   = (const float*)d_in[7];
    const float* b3   = (const float*)d_in[8];
    float* out = (float*)d_out;

    router_mfma<<<NUM_BLOCKS, 256, 0, stream>>>(x, ln_w, ln_b, W1, b1, W2, b2,
                                                W3, b3, out);
}